// Round 13
// baseline (34847.577 us; speedup 1.0000x reference)
//
#include <hip/hip_runtime.h>
#include <hip/hip_cooperative_groups.h>
#include <math.h>

namespace cg = cooperative_groups;

#define BB 128
#define TT 256
#define DD 512
#define HH 1024
#define G4H 4096
#define CO 7
#define XROW (TT * DD)      // x row stride per batch (fp32 elements)
#define LOOFF (BB * HH)     // offset of lo-plane within an h slot (elements)

typedef __attribute__((ext_vector_type(8))) short bf16x8;
typedef __attribute__((ext_vector_type(4))) float f32x4;

__device__ __forceinline__ unsigned short f2bf(float f) {
  unsigned int u = __float_as_uint(f);
  unsigned int r = (u + 0x7fffu + ((u >> 16) & 1u)) >> 16;
  return (unsigned short)r;
}
__device__ __forceinline__ float bf2f(unsigned short h) {
  return __uint_as_float(((unsigned int)h) << 16);
}
__device__ __forceinline__ float tanh_fast(float x) {
  x = fminf(fmaxf(x, -15.f), 15.f);
  const float e = __expf(2.f * x);
  return (e - 1.f) / (e + 1.f);
}
__device__ __forceinline__ float sigmoid_fast(float x) {
  return 1.f / (1.f + __expf(-x));
}
__device__ __forceinline__ void split8(float4 a, float4 b, bf16x8& hi, bf16x8& lo) {
  float f[8] = {a.x, a.y, a.z, a.w, b.x, b.y, b.z, b.w};
  unsigned short h8[8], l8[8];
#pragma unroll
  for (int e = 0; e < 8; ++e) {
    const unsigned short hh = f2bf(f[e]);
    h8[e] = hh;
    l8[e] = f2bf(f[e] - bf2f(hh));
  }
  hi = *(bf16x8*)h8;
  lo = *(bf16x8*)l8;
}

// ------------------------------------------------------------------
// Pack concatenated weights [Wh | Wx] into fragment-major bf16 hi/lo,
// gate-interleaved n-permutation: srow(n) = (n&3)*1024 + (n>>6)*16 + ((n>>2)&15)
// ------------------------------------------------------------------
__global__ __launch_bounds__(256)
void pack_w2(const float* __restrict__ Wh, const float* __restrict__ Wx,
             unsigned short* __restrict__ pk, int Kh, int Kx) {
  const int KS = (Kh + Kx) >> 5;
  const int idx = blockIdx.x * 256 + threadIdx.x;
  const int total = 256 * KS * 64;
  if (idx >= total) return;
  const int l = idx & 63;
  const int t2 = idx >> 6;
  const int ks = t2 % KS;
  const int nt = t2 / KS;
  const int n = (nt << 4) + (l & 15);
  const int srow = ((n & 3) << 10) + ((n >> 6) << 4) + ((n >> 2) & 15);
  const int col = (ks << 5) + ((l >> 4) << 3);
  const float* src = (col < Kh) ? (Wh + (size_t)srow * Kh + col)
                                : (Wx + (size_t)srow * Kx + (col - Kh));
  unsigned short hi[8], lo[8];
#pragma unroll
  for (int e = 0; e < 8; ++e) {
    const float v = src[e];
    const unsigned short h = f2bf(v);
    hi[e] = h;
    lo[e] = f2bf(v - bf2f(h));
  }
  const size_t base = (((size_t)nt * KS + ks) * 2) * 512 + (size_t)l * 8;
  *(uint4*)(pk + base) = *(const uint4*)hi;
  *(uint4*)(pk + base + 512) = *(const uint4*)lo;
}

// LDS buffer layout (64 KB per buffer, two buffers):
//  [0, 32768):      W block: nt*8192 + ksl*2048 + hilo*1024 + l*16
//  [32768, 49152):  A hi bf16: row*256 + ((unit16 ^ (row&15))<<4)   (64 rows x 128 k)
//  [49152, 65536):  A lo bf16 (same addressing)

__device__ __forceinline__ void comp_bf16(const char* buf, int ngoff, int arb, int l4, int l15,
                                          f32x4& acc0, f32x4& acc1) {
#pragma unroll
  for (int ksl = 0; ksl < 4; ++ksl) {
    const bf16x8 wh = *(const bf16x8*)(buf + ngoff + ksl * 2048);
    const bf16x8 wl = *(const bf16x8*)(buf + ngoff + ksl * 2048 + 1024);
    const int so = (((ksl << 2) + l4) ^ l15) << 4;
    const bf16x8 ah0 = *(const bf16x8*)(buf + arb + so);
    const bf16x8 al0 = *(const bf16x8*)(buf + arb + so + 16384);
    const bf16x8 ah1 = *(const bf16x8*)(buf + arb + so + 4096);
    const bf16x8 al1 = *(const bf16x8*)(buf + arb + so + 4096 + 16384);
    acc0 = __builtin_amdgcn_mfma_f32_16x16x32_bf16(ah0, wh, acc0, 0, 0, 0);
    acc0 = __builtin_amdgcn_mfma_f32_16x16x32_bf16(ah0, wl, acc0, 0, 0, 0);
    acc0 = __builtin_amdgcn_mfma_f32_16x16x32_bf16(al0, wh, acc0, 0, 0, 0);
    acc1 = __builtin_amdgcn_mfma_f32_16x16x32_bf16(ah1, wh, acc1, 0, 0, 0);
    acc1 = __builtin_amdgcn_mfma_f32_16x16x32_bf16(ah1, wl, acc1, 0, 0, 0);
    acc1 = __builtin_amdgcn_mfma_f32_16x16x32_bf16(al1, wh, acc1, 0, 0, 0);
  }
}

// common staging/compute macros (shared by persistent + launched kernels)
#define LOADW_M(bb) do {                                      \
    qw0 = *(const uint4*)(pkc0 + (size_t)(bb) * 4096);        \
    qw1 = *(const uint4*)(pkc1 + (size_t)(bb) * 4096);        \
    qw2 = *(const uint4*)(pkc2 + (size_t)(bb) * 4096);        \
    qw3 = *(const uint4*)(pkc3 + (size_t)(bb) * 4096);        \
  } while (0)

#define LOADA_M(bb) do {                                                        \
    if ((bb) < 8) {                                                             \
      const unsigned short* s_ = a1g + ((bb) << 7) + (size_t)aseg * 8;          \
      qa0 = *(const uint4*)s_;           qa1 = *(const uint4*)(s_ + 64);        \
      qa2 = *(const uint4*)(s_ + LOOFF); qa3 = *(const uint4*)(s_ + LOOFF + 64);\
    } else if (layer == 1) {                                                    \
      const unsigned short* s_ = a2g + (((bb) - 8) << 7) + (size_t)aseg * 8;    \
      qa0 = *(const uint4*)s_;           qa1 = *(const uint4*)(s_ + 64);        \
      qa2 = *(const uint4*)(s_ + LOOFF); qa3 = *(const uint4*)(s_ + LOOFF + 64);\
    } else {                                                                    \
      const float* s_ = xg + (((bb) - 8) << 7) + (size_t)aseg * 8;              \
      qa0 = *(const uint4*)s_;        qa1 = *(const uint4*)(s_ + 4);            \
      qa2 = *(const uint4*)(s_ + 64); qa3 = *(const uint4*)(s_ + 68);           \
    }                                                                           \
  } while (0)

#define WRITEB_M(buf, bb) do {                                                  \
    *(uint4*)((buf) + tid * 16)         = qw0;                                  \
    *(uint4*)((buf) + 8192 + tid * 16)  = qw1;                                  \
    *(uint4*)((buf) + 16384 + tid * 16) = qw2;                                  \
    *(uint4*)((buf) + 24576 + tid * 16) = qw3;                                  \
    if ((bb) < 8 || layer == 1) {                                               \
      *(uint4*)((buf) + aw0) = qa0; *(uint4*)((buf) + aw1) = qa1;               \
      *(uint4*)((buf) + aw0 + 16384) = qa2; *(uint4*)((buf) + aw1 + 16384) = qa3; \
    } else {                                                                    \
      bf16x8 xh0, xl0, xh1, xl1;                                                \
      split8(*(float4*)&qa0, *(float4*)&qa1, xh0, xl0);                         \
      split8(*(float4*)&qa2, *(float4*)&qa3, xh1, xl1);                         \
      *(bf16x8*)((buf) + aw0) = xh0; *(bf16x8*)((buf) + aw1) = xh1;             \
      *(bf16x8*)((buf) + aw0 + 16384) = xl0; *(bf16x8*)((buf) + aw1 + 16384) = xl1; \
    }                                                                           \
  } while (0)

// ------------------------------------------------------------------
// PERSISTENT cooperative kernel: one launch, t-loop inside, grid.sync per
// step. Body identical to the proven R6 step_dual. c kept in registers.
// Grid MUST be 256 WGs x 512 thr (1 WG/CU, co-resident).
// ------------------------------------------------------------------
__global__ __launch_bounds__(512, 1)
void lstm_persist(const float* __restrict__ x,
                  const unsigned short* __restrict__ pk0,
                  const unsigned short* __restrict__ pk1,
                  unsigned short* __restrict__ h0s0, unsigned short* __restrict__ h0s1,
                  unsigned short* __restrict__ h1s0, unsigned short* __restrict__ h1s1,
                  const float* __restrict__ bih0, const float* __restrict__ bhh0,
                  const float* __restrict__ bih1, const float* __restrict__ bhh1) {
  __shared__ __align__(16) char lds0[65536];
  __shared__ __align__(16) char lds1[65536];
  cg::grid_group grid = cg::this_grid();

  const int bid = blockIdx.x;
  const int layer = bid >> 7;
  const int lbid = bid & 127;
  const int jg = lbid & 63, bh = lbid >> 6;
  const int tid = threadIdx.x;
  const int wid = tid >> 6, l = tid & 63;
  const int mh = wid & 1, ng = wid >> 1;
  const int l15 = l & 15, l4 = l >> 4;
  const int nl = (ng << 4) + l15;

  const int KS = layer ? 64 : 48;
  const int NB = KS >> 2;
  const unsigned short* pk = layer ? pk1 : pk0;
  const float* bv0 = layer ? bih1 : bih0;
  const float* bv1 = layer ? bhh1 : bhh0;

  // staging maps (t-invariant)
  const int arow = tid >> 3;
  const int aseg = tid & 7;
  const int swA = arow & 15;
  const size_t growHH = (size_t)((bh << 6) + arow) * HH;
  const size_t growX  = (size_t)((bh << 6) + arow) * XROW;

  const unsigned short* pkc0 = pk + ((size_t)(jg * 4 + 0) * KS) * 1024 + (size_t)tid * 8;
  const unsigned short* pkc1 = pk + ((size_t)(jg * 4 + 1) * KS) * 1024 + (size_t)tid * 8;
  const unsigned short* pkc2 = pk + ((size_t)(jg * 4 + 2) * KS) * 1024 + (size_t)tid * 8;
  const unsigned short* pkc3 = pk + ((size_t)(jg * 4 + 3) * KS) * 1024 + (size_t)tid * 8;

  const int aw0 = 32768 + arow * 256 + ((aseg ^ swA) << 4);
  const int aw1 = 32768 + arow * 256 + (((aseg + 8) ^ swA) << 4);
  const int ngoff = ng * 8192 + l * 16;
  const int arb = 32768 + (mh * 32 + l15) * 256;

  // epilogue constants
  const int n = (jg << 6) + nl;
  const int srow = ((n & 3) << 10) + ((n >> 6) << 4) + ((n >> 2) & 15);
  const float bn = bv0[srow] + bv1[srow];
  const int g = nl & 3;
  const int j = (jg << 4) + (nl >> 2);

  float creg[2][4] = {{0.f, 0.f, 0.f, 0.f}, {0.f, 0.f, 0.f, 0.f}};

  for (int t = 0; t <= TT; ++t) {
    const bool active = !((layer == 0 && t >= TT) || (layer == 1 && t < 1));
    if (active) {
      const unsigned short* a1;
      const unsigned short* a2;
      unsigned short* ho;
      if (layer == 0) {
        a1 = (t & 1) ? h0s0 : h0s1;
        ho = (t & 1) ? h0s1 : h0s0;
        a2 = a1;
      } else {
        const int u = t - 1;
        a1 = (u & 1) ? h1s0 : h1s1;
        ho = (u & 1) ? h1s1 : h1s0;
        a2 = (t & 1) ? h0s0 : h0s1;
      }
      const unsigned short* a1g = a1 + growHH;
      const unsigned short* a2g = a2 + growHH;
      const float* xg = x + (size_t)t * DD + growX;

      f32x4 acc0 = (f32x4)(0.f), acc1 = (f32x4)(0.f);
      uint4 qw0, qw1, qw2, qw3, qa0, qa1, qa2, qa3;

      LOADW_M(0); LOADA_M(0);
      WRITEB_M(lds0, 0);
      __syncthreads();

      for (int b = 0; b < NB; ++b) {
        char* cur = (b & 1) ? lds1 : lds0;
        char* nxt = (b & 1) ? lds0 : lds1;
        if (b + 1 < NB) { LOADW_M(b + 1); LOADA_M(b + 1); }
        comp_bf16(cur, ngoff, arb, l4, l15, acc0, acc1);
        if (b + 1 < NB) WRITEB_M(nxt, b + 1);
        __syncthreads();
      }

      f32x4 accs[2] = {acc0, acc1};
#pragma unroll
      for (int mt = 0; mt < 2; ++mt) {
#pragma unroll
        for (int r = 0; r < 4; ++r) {
          const float v = accs[mt][r] + bn;
          const float v1 = __shfl_xor(v, 1);
          const float v2 = __shfl_xor(v, 2);
          const float v3 = __shfl_xor(v, 3);
          if (g == 0) {
            const int b = (bh << 6) + (mh << 5) + (mt << 4) + (l4 << 2) + r;
            const float si = sigmoid_fast(v);
            const float sf = sigmoid_fast(v1);
            const float tg = tanh_fast(v2);
            const float so = sigmoid_fast(v3);
            const float cn = sf * creg[mt][r] + si * tg;
            creg[mt][r] = cn;
            const float h = so * tanh_fast(cn);
            const unsigned short hh = f2bf(h);
            ho[(size_t)b * HH + j] = hh;
            ho[LOOFF + (size_t)b * HH + j] = f2bf(h - bf2f(hh));
          }
        }
      }
    }
    __threadfence();      // release h stores device-wide (cross-XCD)
    grid.sync();
    __threadfence();      // acquire: invalidate stale L2 before next reads
  }
}

// ------------------------------------------------------------------
// Launched fallback step (R6 exact, c in global), used if cooperative
// launch is unavailable.
// ------------------------------------------------------------------
__global__ __launch_bounds__(512, 1)
void step_dual(int t,
               const float* __restrict__ x,
               const unsigned short* __restrict__ pk0,
               const unsigned short* __restrict__ pk1,
               unsigned short* __restrict__ h0s0, unsigned short* __restrict__ h0s1,
               unsigned short* __restrict__ h1s0, unsigned short* __restrict__ h1s1,
               const float* __restrict__ bih0, const float* __restrict__ bhh0,
               const float* __restrict__ bih1, const float* __restrict__ bhh1,
               float* __restrict__ c0, float* __restrict__ c1) {
  __shared__ __align__(16) char lds0[65536];
  __shared__ __align__(16) char lds1[65536];
  const int bid = blockIdx.x;
  const int layer = bid >> 7;
  if (layer == 0 && t >= TT) return;
  if (layer == 1 && t < 1) return;
  const int lbid = bid & 127;
  const int jg = lbid & 63, bh = lbid >> 6;
  const int tid = threadIdx.x;
  const int wid = tid >> 6, l = tid & 63;
  const int mh = wid & 1, ng = wid >> 1;
  const int l15 = l & 15, l4 = l >> 4;
  const int nl = (ng << 4) + l15;

  const int KS = layer ? 64 : 48;
  const int NB = KS >> 2;
  const unsigned short* pk = layer ? pk1 : pk0;
  const unsigned short* a1;
  const unsigned short* a2;
  unsigned short* ho;
  float* cb;
  const float* bv0;
  const float* bv1;
  if (layer == 0) {
    a1 = (t & 1) ? h0s0 : h0s1;
    ho = (t & 1) ? h0s1 : h0s0;
    a2 = a1;
    cb = c0; bv0 = bih0; bv1 = bhh0;
  } else {
    const int u = t - 1;
    a1 = (u & 1) ? h1s0 : h1s1;
    ho = (u & 1) ? h1s1 : h1s0;
    a2 = (t & 1) ? h0s0 : h0s1;
    cb = c1; bv0 = bih1; bv1 = bhh1;
  }

  const int arow = tid >> 3;
  const int aseg = tid & 7;
  const int swA = arow & 15;
  const size_t growA = (size_t)((bh << 6) + arow);
  const unsigned short* a1g = a1 + growA * HH;
  const unsigned short* a2g = a2 + growA * HH;
  const float* xg = x + (size_t)t * DD + growA * XROW;

  const unsigned short* pkc0 = pk + ((size_t)(jg * 4 + 0) * KS) * 1024 + (size_t)tid * 8;
  const unsigned short* pkc1 = pk + ((size_t)(jg * 4 + 1) * KS) * 1024 + (size_t)tid * 8;
  const unsigned short* pkc2 = pk + ((size_t)(jg * 4 + 2) * KS) * 1024 + (size_t)tid * 8;
  const unsigned short* pkc3 = pk + ((size_t)(jg * 4 + 3) * KS) * 1024 + (size_t)tid * 8;

  const int aw0 = 32768 + arow * 256 + ((aseg ^ swA) << 4);
  const int aw1 = 32768 + arow * 256 + (((aseg + 8) ^ swA) << 4);
  const int ngoff = ng * 8192 + l * 16;
  const int arb = 32768 + (mh * 32 + l15) * 256;

  f32x4 acc0 = (f32x4)(0.f), acc1 = (f32x4)(0.f);
  uint4 qw0, qw1, qw2, qw3, qa0, qa1, qa2, qa3;

  LOADW_M(0); LOADA_M(0);
  WRITEB_M(lds0, 0);
  __syncthreads();

  for (int b = 0; b < NB; ++b) {
    char* cur = (b & 1) ? lds1 : lds0;
    char* nxt = (b & 1) ? lds0 : lds1;
    if (b + 1 < NB) { LOADW_M(b + 1); LOADA_M(b + 1); }
    comp_bf16(cur, ngoff, arb, l4, l15, acc0, acc1);
    if (b + 1 < NB) WRITEB_M(nxt, b + 1);
    __syncthreads();
  }

  const int n = (jg << 6) + nl;
  const int srow = ((n & 3) << 10) + ((n >> 6) << 4) + ((n >> 2) & 15);
  const float bn = bv0[srow] + bv1[srow];
  const int g = nl & 3;
  const int j = (jg << 4) + (nl >> 2);
  f32x4 accs[2] = {acc0, acc1};
#pragma unroll
  for (int mt = 0; mt < 2; ++mt) {
#pragma unroll
    for (int r = 0; r < 4; ++r) {
      const float v = accs[mt][r] + bn;
      const float v1 = __shfl_xor(v, 1);
      const float v2 = __shfl_xor(v, 2);
      const float v3 = __shfl_xor(v, 3);
      if (g == 0) {
        const int b = (bh << 6) + (mh << 5) + (mt << 4) + (l4 << 2) + r;
        const float si = sigmoid_fast(v);
        const float sf = sigmoid_fast(v1);
        const float tg = tanh_fast(v2);
        const float so = sigmoid_fast(v3);
        const size_t ci = (size_t)b * HH + j;
        const float cn = sf * cb[ci] + si * tg;
        cb[ci] = cn;
        const float h = so * tanh_fast(cn);
        const unsigned short hh = f2bf(h);
        ho[(size_t)b * HH + j] = hh;
        ho[LOOFF + (size_t)b * HH + j] = f2bf(h - bf2f(hh));
      }
    }
  }
}

// ------------------------------------------------------------------
// FC from hi/lo h slot
// ------------------------------------------------------------------
__global__ __launch_bounds__(256)
void fc_hilo(const unsigned short* __restrict__ hhi, const unsigned short* __restrict__ hlo,
             const float* __restrict__ fcw, const float* __restrict__ fcb,
             float* __restrict__ out) {
  const int gw = (int)((blockIdx.x * 256 + threadIdx.x) >> 6);
  const int lane = threadIdx.x & 63;
  const int b = gw / CO;
  const int n = gw - b * CO;
  const unsigned short* hp = hhi + (size_t)b * HH;
  const unsigned short* lp = hlo + (size_t)b * HH;
  const float* wp = fcw + (size_t)n * HH;
  float s = 0.f;
  for (int k = lane; k < HH; k += 64) s += (bf2f(hp[k]) + bf2f(lp[k])) * wp[k];
#pragma unroll
  for (int off = 32; off; off >>= 1) s += __shfl_down(s, off);
  if (lane == 0) out[b * CO + n] = s + fcb[n];
}

// ==================================================================
// Fallback fp32 path (round-2 kernels, used only if ws_size is small)
// ==================================================================
__global__ __launch_bounds__(256)
void gemm_bias(const float* __restrict__ A, long long sOut, long long sIn, int lt,
               const float* __restrict__ W,
               const float* __restrict__ b0, const float* __restrict__ b1,
               float* __restrict__ C, int N, int K) {
  __shared__ float as[16][64];
  __shared__ float wsh[16][64];
  const int tid = threadIdx.x;
  const int bm = blockIdx.y << 6;
  const int bn = blockIdx.x << 6;
  const int tr = (tid >> 4) << 2;
  const int tc = (tid & 15) << 2;
  const int lrow = tid >> 2;
  const int lk4 = (tid & 3) << 2;
  const int msk = (1 << lt) - 1;
  const int r = bm + lrow;
  const float* ap = A + (size_t)(r >> lt) * sOut + (size_t)(r & msk) * sIn + lk4;
  const float* wp = W + (size_t)(bn + lrow) * K + lk4;
  float acc[4][4] = {};
  for (int k0 = 0; k0 < K; k0 += 16) {
    const float4 av = *(const float4*)(ap + k0);
    const float4 wv = *(const float4*)(wp + k0);
    __syncthreads();
    as[lk4 + 0][lrow] = av.x; as[lk4 + 1][lrow] = av.y;
    as[lk4 + 2][lrow] = av.z; as[lk4 + 3][lrow] = av.w;
    wsh[lk4 + 0][lrow] = wv.x; wsh[lk4 + 1][lrow] = wv.y;
    wsh[lk4 + 2][lrow] = wv.z; wsh[lk4 + 3][lrow] = wv.w;
    __syncthreads();
#pragma unroll
    for (int k = 0; k < 16; ++k) {
      const float4 a = *(const float4*)&as[k][tr];
      const float4 b = *(const float4*)&wsh[k][tc];
      acc[0][0] += a.x * b.x; acc[0][1] += a.x * b.y; acc[0][2] += a.x * b.z; acc[0][3] += a.x * b.w;
      acc[1][0] += a.y * b.x; acc[1][1] += a.y * b.y; acc[1][2] += a.y * b.z; acc[1][3] += a.y * b.w;
      acc[2][0] += a.z * b.x; acc[2][1] += a.z * b.y; acc[2][2] += a.z * b.z; acc[2][3] += a.z * b.w;
      acc[3][0] += a.w * b.x; acc[3][1] += a.w * b.y; acc[3][2] += a.w * b.z; acc[3][3] += a.w * b.w;
    }
  }
  const float* bp0 = b0 + bn + tc;
  const float* bp1 = b1 + bn + tc;
#pragma unroll
  for (int i = 0; i < 4; ++i) {
    float* cp = C + (size_t)(bm + tr + i) * N + bn + tc;
#pragma unroll
    for (int j = 0; j < 4; ++j) cp[j] = acc[i][j] + bp0[j] + bp1[j];
  }
}

__global__ __launch_bounds__(256)
void lstm_step(const float* __restrict__ gx, long long gxstride,
               const float* __restrict__ whh,
               const float* __restrict__ hprev, long long pstride,
               float* __restrict__ hnext, long long nstride,
               float* __restrict__ cbuf) {
  __shared__ float hs[32][16];
  __shared__ float wsm[32][4][32];
  const int tid = threadIdx.x;
  const int jt = blockIdx.x << 5;
  const int bm = blockIdx.y << 4;
  const int col = tid & 31;
  const int rp = (tid >> 5) << 1;
  const int hr = tid >> 4;
  const int hk = (tid & 15) << 1;
  const int wrow = tid & 127;
  const int wg = wrow >> 5;
  const int wc = wrow & 31;
  const int wk = (tid >> 7) << 4;
  const float* wbase = whh + (size_t)(wg * HH + jt + wc) * HH + wk;
  const float* hbase = hprev + (size_t)(bm + hr) * pstride + hk;

  float acc[4][2] = {};
  for (int k0 = 0; k0 < HH; k0 += 32) {
    const float2 hv = *(const float2*)(hbase + k0);
    const float4 wv0 = *(const float4*)(wbase + k0);
    const float4 wv1 = *(const float4*)(wbase + k0 + 4);
    const float4 wv2 = *(const float4*)(wbase + k0 + 8);
    const float4 wv3 = *(const float4*)(wbase + k0 + 12);
    __syncthreads();
    hs[hk][hr] = hv.x; hs[hk + 1][hr] = hv.y;
    {
      const float wvv[16] = {wv0.x, wv0.y, wv0.z, wv0.w, wv1.x, wv1.y, wv1.z, wv1.w,
                             wv2.x, wv2.y, wv2.z, wv2.w, wv3.x, wv3.y, wv3.z, wv3.w};
#pragma unroll
      for (int i = 0; i < 16; ++i) wsm[wk + i][wg][wc] = wvv[i];
    }
    __syncthreads();
#pragma unroll
    for (int k = 0; k < 32; ++k) {
      const float2 a = *(const float2*)&hs[k][rp];
      const float wi = wsm[k][0][col];
      const float wf = wsm[k][1][col];
      const float wg_ = wsm[k][2][col];
      const float wo = wsm[k][3][col];
      acc[0][0] += a.x * wi;  acc[0][1] += a.y * wi;
      acc[1][0] += a.x * wf;  acc[1][1] += a.y * wf;
      acc[2][0] += a.x * wg_; acc[2][1] += a.y * wg_;
      acc[3][0] += a.x * wo;  acc[3][1] += a.y * wo;
    }
  }
#pragma unroll
  for (int rr = 0; rr < 2; ++rr) {
    const int b = bm + rp + rr;
    const int j = jt + col;
    const size_t gxo = (size_t)b * gxstride + j;
    const float gi = acc[0][rr] + gx[gxo];
    const float gf = acc[1][rr] + gx[gxo + HH];
    const float gg = acc[2][rr] + gx[gxo + 2 * HH];
    const float go = acc[3][rr] + gx[gxo + 3 * HH];
    const float si = 1.f / (1.f + expf(-gi));
    const float sf = 1.f / (1.f + expf(-gf));
    const float so = 1.f / (1.f + expf(-go));
    const size_t cidx = (size_t)b * HH + j;
    const float cn = sf * cbuf[cidx] + si * tanhf(gg);
    cbuf[cidx] = cn;
    hnext[(size_t)b * nstride + j] = so * tanhf(cn);
  }
}

__global__ __launch_bounds__(256)
void fc_kernel(const float* __restrict__ hlast, const float* __restrict__ fcw,
               const float* __restrict__ fcb, float* __restrict__ out) {
  const int gw = (int)((blockIdx.x * 256 + threadIdx.x) >> 6);
  const int lane = threadIdx.x & 63;
  const int b = gw / CO;
  const int n = gw - b * CO;
  const float* hp = hlast + (size_t)b * HH;
  const float* wp = fcw + (size_t)n * HH;
  float s = 0.f;
  for (int k = lane; k < HH; k += 64) s += hp[k] * wp[k];
#pragma unroll
  for (int off = 32; off; off >>= 1) s += __shfl_down(s, off);
  if (lane == 0) out[b * CO + n] = s + fcb[n];
}

// ==================================================================
extern "C" void kernel_launch(void* const* d_in, const int* in_sizes, int n_in,
                              void* d_out, int out_size, void* d_ws, size_t ws_size,
                              hipStream_t stream) {
  const float* x    = (const float*)d_in[0];
  const float* wih0 = (const float*)d_in[1];
  const float* whh0 = (const float*)d_in[2];
  const float* bih0 = (const float*)d_in[3];
  const float* bhh0 = (const float*)d_in[4];
  const float* wih1 = (const float*)d_in[5];
  const float* whh1 = (const float*)d_in[6];
  const float* bih1 = (const float*)d_in[7];
  const float* bhh1 = (const float*)d_in[8];
  const float* fcw  = (const float*)d_in[9];
  const float* fcb  = (const float*)d_in[10];
  float* out = (float*)d_out;

  // ---- MFMA-path workspace ----
  const size_t pk0B  = (size_t)256 * 48 * 1024 * 2;   // 25,165,824 B
  const size_t pk1B  = (size_t)256 * 64 * 1024 * 2;   // 33,554,432 B
  const size_t slotB = 2 * (size_t)BB * HH * 2;       // 524,288 B (hi+lo)
  const size_t cB    = (size_t)BB * HH * 4;           // 524,288 B
  const size_t needB = pk0B + pk1B + 4 * slotB + 2 * cB;  // 61,865,984 B

  if (needB <= ws_size) {
    char* p = (char*)d_ws;
    unsigned short* pk0  = (unsigned short*)p; p += pk0B;
    unsigned short* pk1  = (unsigned short*)p; p += pk1B;
    unsigned short* h0s0 = (unsigned short*)p; p += slotB;
    unsigned short* h1s0 = (unsigned short*)p; p += slotB;
    char* zblock = p;                         // h0s1, h1s1, c0, c1 (zeroed)
    unsigned short* h0s1 = (unsigned short*)p; p += slotB;
    unsigned short* h1s1 = (unsigned short*)p; p += slotB;
    float* c0 = (float*)p; p += cB;
    float* c1 = (float*)p; p += cB;

    hipMemsetAsync(zblock, 0, 2 * slotB + 2 * cB, stream);

    pack_w2<<<dim3((256 * 48 * 64) / 256), 256, 0, stream>>>(whh0, wih0, pk0, HH, DD);
    pack_w2<<<dim3((256 * 64 * 64) / 256), 256, 0, stream>>>(whh1, wih1, pk1, HH, HH);

    // ---- persistent cooperative path ----
    void* args[] = {(void*)&x, (void*)&pk0, (void*)&pk1,
                    (void*)&h0s0, (void*)&h0s1, (void*)&h1s0, (void*)&h1s1,
                    (void*)&bih0, (void*)&bhh0, (void*)&bih1, (void*)&bhh1};
    hipError_t ce = hipLaunchCooperativeKernel((void*)lstm_persist,
                                               dim3(256), dim3(512), args, 0, stream);
    if (ce != hipSuccess) {
      // fallback: 257 dependent launches (R6 path)
      for (int t = 0; t <= TT; ++t) {
        step_dual<<<dim3(256), 512, 0, stream>>>(t, x, pk0, pk1,
                                                 h0s0, h0s1, h1s0, h1s1,
                                                 bih0, bhh0, bih1, bhh1, c0, c1);
      }
    }

    // final u = 255 (odd) wrote slot[1] = h1s1
    fc_hilo<<<dim3((BB * CO * 64) / 256), 256, 0, stream>>>(h1s1, h1s1 + LOOFF,
                                                            fcw, fcb, out);
    return;
  }

  // ---------------- fallback fp32 path ----------------
  {
    int Tc2 = 64, lt2 = 6;
    while (Tc2 > 1) {
      size_t need = ((size_t)655360 * (size_t)Tc2 + 4u * 131072u + 1024u) * 4u;
      if (need <= ws_size) break;
      Tc2 >>= 1; --lt2;
    }
    float* ws  = (float*)d_ws;
    float* gxc = ws;
    float* hc  = gxc + (size_t)BB * Tc2 * G4H;
    float* c0  = hc + (size_t)BB * Tc2 * HH;
    float* c1  = c0 + (size_t)BB * HH;
    float* h2a = c1 + (size_t)BB * HH;
    float* h2b = h2a + (size_t)BB * HH;
    float* zb  = h2b + (size_t)BB * HH;

    hipMemsetAsync(zb, 0, HH * sizeof(float), stream);
    hipMemsetAsync(c0, 0, (size_t)BB * HH * sizeof(float), stream);
    hipMemsetAsync(c1, 0, (size_t)BB * HH * sizeof(float), stream);

    const dim3 gGemm(G4H / 64, (BB * Tc2) / 64);
    const dim3 gStep(HH / 32, BB / 16);
    const long long gxs = (long long)Tc2 * G4H;
    const long long hcs = (long long)Tc2 * HH;

    const int nChunks = TT / Tc2;
    for (int ci = 0; ci < nChunks; ++ci) {
      const int t0 = ci * Tc2;
      gemm_bias<<<gGemm, 256, 0, stream>>>(x + (size_t)t0 * DD, (long long)TT * DD,
                                           (long long)DD, lt2, wih0, bih0, bhh0,
                                           gxc, G4H, DD);
      for (int tl = 0; tl < Tc2; ++tl) {
        const int t = t0 + tl;
        const float* hprev;
        long long ps;
        if (t == 0) { hprev = zb; ps = 0; }
        else {
          const int ptl = (tl == 0) ? (Tc2 - 1) : (tl - 1);
          hprev = hc + (size_t)ptl * HH; ps = hcs;
        }
        lstm_step<<<gStep, 256, 0, stream>>>(gxc + (size_t)tl * G4H, gxs, whh0,
                                             hprev, ps, hc + (size_t)tl * HH, hcs, c0);
      }
      gemm_bias<<<gGemm, 256, 0, stream>>>(hc, hcs, (long long)HH, lt2,
                                           wih1, bih1, bhh1, gxc, G4H, HH);
      for (int tl = 0; tl < Tc2; ++tl) {
        const int t = t0 + tl;
        const float* hprev;
        long long ps;
        if (t == 0) { hprev = zb; ps = 0; }
        else { hprev = ((t - 1) & 1) ? h2b : h2a; ps = HH; }
        float* hnext = (t & 1) ? h2b : h2a;
        lstm_step<<<gStep, 256, 0, stream>>>(gxc + (size_t)tl * G4H, gxs, whh1,
                                             hprev, ps, hnext, HH, c1);
      }
    }
    fc_kernel<<<dim3((BB * CO * 64) / 256), 256, 0, stream>>>(h2b, fcw, fcb, out);
  }
}

// Round 14
// 7754.162 us; speedup vs baseline: 4.4940x; 4.4940x over previous
//
#include <hip/hip_runtime.h>
#include <math.h>

#define BB 128
#define TT 256
#define DD 512
#define HH 1024
#define G4H 4096
#define CO 7
#define XROW (TT * DD)      // x row stride per batch (fp32 elements)
#define LOOFF (BB * HH)     // offset of lo-plane within an h slot (elements)
#define RS 17               // ring slots per layer (>= CHUNK+1)
#define CHUNK 16
#define SLOTE (2 * BB * HH) // elements per ring slot (hi+lo planes)

typedef __attribute__((ext_vector_type(8))) short bf16x8;
typedef __attribute__((ext_vector_type(4))) float f32x4;

__device__ __forceinline__ unsigned short f2bf(float f) {
  unsigned int u = __float_as_uint(f);
  unsigned int r = (u + 0x7fffu + ((u >> 16) & 1u)) >> 16;
  return (unsigned short)r;
}
__device__ __forceinline__ float bf2f(unsigned short h) {
  return __uint_as_float(((unsigned int)h) << 16);
}
__device__ __forceinline__ float tanh_fast(float x) {
  x = fminf(fmaxf(x, -15.f), 15.f);
  const float e = __expf(2.f * x);
  return (e - 1.f) / (e + 1.f);
}
__device__ __forceinline__ float sigmoid_fast(float x) {
  return 1.f / (1.f + __expf(-x));
}
__device__ __forceinline__ void split8(float4 a, float4 b, bf16x8& hi, bf16x8& lo) {
  float f[8] = {a.x, a.y, a.z, a.w, b.x, b.y, b.z, b.w};
  unsigned short h8[8], l8[8];
#pragma unroll
  for (int e = 0; e < 8; ++e) {
    const unsigned short hh = f2bf(f[e]);
    h8[e] = hh;
    l8[e] = f2bf(f[e] - bf2f(hh));
  }
  hi = *(bf16x8*)h8;
  lo = *(bf16x8*)l8;
}

// ------------------------------------------------------------------
// Pack [Wh | Wx] into fragment-major bf16 HI-ONLY, gate-interleaved perm:
// srow(n) = (n&3)*1024 + (n>>6)*16 + ((n>>2)&15)
// pk[(nt*KS + ks)*512 + l*8 + e] = src[srow(nt*16+(l&15))][ks*32+(l>>4)*8+e]
// ------------------------------------------------------------------
__global__ __launch_bounds__(256)
void pack_w1(const float* __restrict__ Wh, const float* __restrict__ Wx,
             unsigned short* __restrict__ pk, int Kh, int Kx) {
  const int KS = (Kh + Kx) >> 5;
  const int idx = blockIdx.x * 256 + threadIdx.x;
  const int total = 256 * KS * 64;
  if (idx >= total) return;
  const int l = idx & 63;
  const int t2 = idx >> 6;
  const int ks = t2 % KS;
  const int nt = t2 / KS;
  const int n = (nt << 4) + (l & 15);
  const int srow = ((n & 3) << 10) + ((n >> 6) << 4) + ((n >> 2) & 15);
  const int col = (ks << 5) + ((l >> 4) << 3);
  const float* src = (col < Kh) ? (Wh + (size_t)srow * Kh + col)
                                : (Wx + (size_t)srow * Kx + (col - Kh));
  unsigned short hi[8];
#pragma unroll
  for (int e = 0; e < 8; ++e) hi[e] = f2bf(src[e]);
  const size_t base = ((size_t)nt * KS + ks) * 512 + (size_t)l * 8;
  *(uint4*)(pk + base) = *(const uint4*)hi;
}

// LDS buffer layout (49152 B per buffer, two buffers):
//  [0, 16384):      W block (hi only): nt*4096 + ksl*1024 + l*16
//  [16384, 32768):  A hi bf16: row*256 + ((unit16 ^ (row&15))<<4)  (64 rows x 128 k)
//  [32768, 49152):  A lo bf16 (same addressing)

__device__ __forceinline__ void comp_w1(const char* buf, int ngoff, int arb, int l4, int l15,
                                        f32x4& acc0, f32x4& acc1) {
#pragma unroll
  for (int ksl = 0; ksl < 4; ++ksl) {
    const bf16x8 wh = *(const bf16x8*)(buf + ngoff + ksl * 1024);
    const int so = (((ksl << 2) + l4) ^ l15) << 4;
    const bf16x8 ah0 = *(const bf16x8*)(buf + arb + so);
    const bf16x8 al0 = *(const bf16x8*)(buf + arb + so + 16384);
    const bf16x8 ah1 = *(const bf16x8*)(buf + arb + so + 4096);
    const bf16x8 al1 = *(const bf16x8*)(buf + arb + so + 4096 + 16384);
    acc0 = __builtin_amdgcn_mfma_f32_16x16x32_bf16(ah0, wh, acc0, 0, 0, 0);
    acc0 = __builtin_amdgcn_mfma_f32_16x16x32_bf16(al0, wh, acc0, 0, 0, 0);
    acc1 = __builtin_amdgcn_mfma_f32_16x16x32_bf16(ah1, wh, acc1, 0, 0, 0);
    acc1 = __builtin_amdgcn_mfma_f32_16x16x32_bf16(al1, wh, acc1, 0, 0, 0);
  }
}

// ------------------------------------------------------------------
// Multi-step diagonal chunk kernel (cooperative co-residency assumed when
// len > 1). WGs 0..127 = layer0 @ t, 128..255 = layer1 @ t-1.
// h lives in write-once rings (RS slots): producers store with agent scope
// (bypass L2 -> coherent point); consumers first-touch each address after
// the flush-free atomic-counter barrier. W (hi-only) stays L2-resident.
// ------------------------------------------------------------------
__global__ __launch_bounds__(512, 1)
void lstm_chunk(int t0, int len, int barBase,
                const float* __restrict__ x,
                const unsigned short* __restrict__ pk0,
                const unsigned short* __restrict__ pk1,
                unsigned short* __restrict__ ring0,
                unsigned short* __restrict__ ring1,
                const float* __restrict__ bih0, const float* __restrict__ bhh0,
                const float* __restrict__ bih1, const float* __restrict__ bhh1,
                float* __restrict__ c0, float* __restrict__ c1,
                unsigned* __restrict__ barcnt) {
  __shared__ __align__(16) char lds0[49152];
  __shared__ __align__(16) char lds1[49152];
  const int bid = blockIdx.x;
  const int layer = bid >> 7;
  const int lbid = bid & 127;
  const int jg = lbid & 63, bh = lbid >> 6;
  const int tid = threadIdx.x;
  const int wid = tid >> 6, l = tid & 63;
  const int mh = wid & 1, ng = wid >> 1;
  const int l15 = l & 15, l4 = l >> 4;
  const int nl = (ng << 4) + l15;

  const int KS = layer ? 64 : 48;
  const int NB = KS >> 2;
  const unsigned short* pk = layer ? pk1 : pk0;
  const float* bv0 = layer ? bih1 : bih0;
  const float* bv1 = layer ? bhh1 : bhh0;
  float* cb = layer ? c1 : c0;

  // A staging maps (t-invariant)
  const int arow = tid >> 3;
  const int aseg = tid & 7;
  const int swA = arow & 15;
  const size_t growHH = (size_t)((bh << 6) + arow) * HH;
  const size_t growX  = (size_t)((bh << 6) + arow) * XROW;

  // W staging (hi-only): thread stages 2 frag-words; dest is LDS-linear.
  const int ntA = tid >> 8;                 // 0..1
  const int kslA = (tid & 255) >> 6;        // 0..3
  const int lA = tid & 63;
  const unsigned short* pkcA = pk + ((size_t)(jg * 4 + ntA) * KS + kslA) * 512 + (size_t)lA * 8;
  const unsigned short* pkcB = pk + ((size_t)(jg * 4 + 2 + ntA) * KS + kslA) * 512 + (size_t)lA * 8;

  const int aw0 = 16384 + arow * 256 + ((aseg ^ swA) << 4);
  const int aw1 = 16384 + arow * 256 + (((aseg + 8) ^ swA) << 4);
  const int ngoff = ng * 4096 + l * 16;
  const int arb = 16384 + (mh * 32 + l15) * 256;

  // epilogue constants
  const int n = (jg << 6) + nl;
  const int srow = ((n & 3) << 10) + ((n >> 6) << 4) + ((n >> 2) & 15);
  const float bn = bv0[srow] + bv1[srow];
  const int g = nl & 3;
  const int j = (jg << 4) + (nl >> 2);

#define LOADW_C(bb) do {                                      \
    qwA = *(const uint4*)(pkcA + (size_t)(bb) * 2048);        \
    qwB = *(const uint4*)(pkcB + (size_t)(bb) * 2048);        \
  } while (0)

#define LOADA_C(bb) do {                                                        \
    if ((bb) < 8) {                                                             \
      const unsigned short* s_ = a1g + ((bb) << 7) + (size_t)aseg * 8;          \
      qa0 = *(const uint4*)s_;           qa1 = *(const uint4*)(s_ + 64);        \
      qa2 = *(const uint4*)(s_ + LOOFF); qa3 = *(const uint4*)(s_ + LOOFF + 64);\
    } else if (layer == 1) {                                                    \
      const unsigned short* s_ = a2g + (((bb) - 8) << 7) + (size_t)aseg * 8;    \
      qa0 = *(const uint4*)s_;           qa1 = *(const uint4*)(s_ + 64);        \
      qa2 = *(const uint4*)(s_ + LOOFF); qa3 = *(const uint4*)(s_ + LOOFF + 64);\
    } else {                                                                    \
      const float* s_ = xg + (((bb) - 8) << 7) + (size_t)aseg * 8;              \
      qa0 = *(const uint4*)s_;        qa1 = *(const uint4*)(s_ + 4);            \
      qa2 = *(const uint4*)(s_ + 64); qa3 = *(const uint4*)(s_ + 68);           \
    }                                                                           \
  } while (0)

#define WRITEB_C(buf, bb) do {                                                  \
    *(uint4*)((buf) + tid * 16)        = qwA;                                   \
    *(uint4*)((buf) + 8192 + tid * 16) = qwB;                                   \
    if ((bb) < 8 || layer == 1) {                                               \
      *(uint4*)((buf) + aw0) = qa0; *(uint4*)((buf) + aw1) = qa1;               \
      *(uint4*)((buf) + aw0 + 16384) = qa2; *(uint4*)((buf) + aw1 + 16384) = qa3; \
    } else {                                                                    \
      bf16x8 xh0, xl0, xh1, xl1;                                                \
      split8(*(float4*)&qa0, *(float4*)&qa1, xh0, xl0);                         \
      split8(*(float4*)&qa2, *(float4*)&qa3, xh1, xl1);                         \
      *(bf16x8*)((buf) + aw0) = xh0; *(bf16x8*)((buf) + aw1) = xh1;             \
      *(bf16x8*)((buf) + aw0 + 16384) = xl0; *(bf16x8*)((buf) + aw1 + 16384) = xl1; \
    }                                                                           \
  } while (0)

  for (int tt = 0; tt < len; ++tt) {
    const int t = t0 + tt;
    const bool active = !((layer == 0 && t >= TT) || (layer == 1 && t < 1));
    if (active) {
      const unsigned short* a1;
      const unsigned short* a2;
      unsigned short* ho;
      if (layer == 0) {
        a1 = ring0 + (size_t)(t % RS) * SLOTE;          // h0[t-1]
        ho = ring0 + (size_t)((t + 1) % RS) * SLOTE;    // h0[t]
        a2 = a1;
      } else {
        a1 = ring1 + (size_t)((t - 1) % RS) * SLOTE;    // h1[t-2]
        ho = ring1 + (size_t)(t % RS) * SLOTE;          // h1[t-1]
        a2 = ring0 + (size_t)(t % RS) * SLOTE;          // h0[t-1]
      }
      const unsigned short* a1g = a1 + growHH;
      const unsigned short* a2g = a2 + growHH;
      const float* xg = x + (size_t)t * DD + growX;

      f32x4 acc0 = (f32x4)(0.f), acc1 = (f32x4)(0.f);
      uint4 qwA, qwB, qa0, qa1, qa2, qa3;

      LOADW_C(0); LOADA_C(0);
      WRITEB_C(lds0, 0);
      __syncthreads();

      for (int b = 0; b < NB; ++b) {
        char* cur = (b & 1) ? lds1 : lds0;
        char* nxt = (b & 1) ? lds0 : lds1;
        if (b + 1 < NB) { LOADW_C(b + 1); LOADA_C(b + 1); }
        comp_w1(cur, ngoff, arb, l4, l15, acc0, acc1);
        if (b + 1 < NB) WRITEB_C(nxt, b + 1);
        __syncthreads();
      }

      f32x4 accs[2] = {acc0, acc1};
#pragma unroll
      for (int mt = 0; mt < 2; ++mt) {
#pragma unroll
        for (int r = 0; r < 4; ++r) {
          const float v = accs[mt][r] + bn;
          const float v1 = __shfl_xor(v, 1);
          const float v2 = __shfl_xor(v, 2);
          const float v3 = __shfl_xor(v, 3);
          if (g == 0) {
            const int b = (bh << 6) + (mh << 5) + (mt << 4) + (l4 << 2) + r;
            const float si = sigmoid_fast(v);
            const float sf = sigmoid_fast(v1);
            const float tg = tanh_fast(v2);
            const float so = sigmoid_fast(v3);
            const size_t ci = (size_t)b * HH + j;
            const float cn = sf * cb[ci] + si * tg;
            cb[ci] = cn;
            const float h = so * tanh_fast(cn);
            const unsigned short hh = f2bf(h);
            const unsigned short hl = f2bf(h - bf2f(hh));
            // agent-scope stores: bypass L2, land at coherent point
            __hip_atomic_store(&ho[(size_t)b * HH + j], hh,
                               __ATOMIC_RELAXED, __HIP_MEMORY_SCOPE_AGENT);
            __hip_atomic_store(&ho[LOOFF + (size_t)b * HH + j], hl,
                               __ATOMIC_RELAXED, __HIP_MEMORY_SCOPE_AGENT);
          }
        }
      }
    }
    // flush-free grid barrier (skip after last step: kernel end is stronger)
    if (tt + 1 < len) {
      __syncthreads();   // per-wave vmcnt drain: h stores are globally visible
      if (tid == 0) {
        __hip_atomic_fetch_add(barcnt, 1u, __ATOMIC_RELAXED, __HIP_MEMORY_SCOPE_AGENT);
        const unsigned tgt = 256u * (unsigned)(barBase + tt + 1);
        while (__hip_atomic_load(barcnt, __ATOMIC_RELAXED, __HIP_MEMORY_SCOPE_AGENT) < tgt)
          __builtin_amdgcn_s_sleep(2);
      }
      __syncthreads();
    }
  }
#undef LOADW_C
#undef LOADA_C
#undef WRITEB_C
}

// ------------------------------------------------------------------
// FC from hi/lo h slot
// ------------------------------------------------------------------
__global__ __launch_bounds__(256)
void fc_hilo(const unsigned short* __restrict__ hhi, const unsigned short* __restrict__ hlo,
             const float* __restrict__ fcw, const float* __restrict__ fcb,
             float* __restrict__ out) {
  const int gw = (int)((blockIdx.x * 256 + threadIdx.x) >> 6);
  const int lane = threadIdx.x & 63;
  const int b = gw / CO;
  const int n = gw - b * CO;
  const unsigned short* hp = hhi + (size_t)b * HH;
  const unsigned short* lp = hlo + (size_t)b * HH;
  const float* wp = fcw + (size_t)n * HH;
  float s = 0.f;
  for (int k = lane; k < HH; k += 64) s += (bf2f(hp[k]) + bf2f(lp[k])) * wp[k];
#pragma unroll
  for (int off = 32; off; off >>= 1) s += __shfl_down(s, off);
  if (lane == 0) out[b * CO + n] = s + fcb[n];
}

// ==================================================================
// Fallback fp32 path (round-2 kernels, used only if ws_size is small)
// ==================================================================
__global__ __launch_bounds__(256)
void gemm_bias(const float* __restrict__ A, long long sOut, long long sIn, int lt,
               const float* __restrict__ W,
               const float* __restrict__ b0, const float* __restrict__ b1,
               float* __restrict__ C, int N, int K) {
  __shared__ float as[16][64];
  __shared__ float wsh[16][64];
  const int tid = threadIdx.x;
  const int bm = blockIdx.y << 6;
  const int bn = blockIdx.x << 6;
  const int tr = (tid >> 4) << 2;
  const int tc = (tid & 15) << 2;
  const int lrow = tid >> 2;
  const int lk4 = (tid & 3) << 2;
  const int msk = (1 << lt) - 1;
  const int r = bm + lrow;
  const float* ap = A + (size_t)(r >> lt) * sOut + (size_t)(r & msk) * sIn + lk4;
  const float* wp = W + (size_t)(bn + lrow) * K + lk4;
  float acc[4][4] = {};
  for (int k0 = 0; k0 < K; k0 += 16) {
    const float4 av = *(const float4*)(ap + k0);
    const float4 wv = *(const float4*)(wp + k0);
    __syncthreads();
    as[lk4 + 0][lrow] = av.x; as[lk4 + 1][lrow] = av.y;
    as[lk4 + 2][lrow] = av.z; as[lk4 + 3][lrow] = av.w;
    wsh[lk4 + 0][lrow] = wv.x; wsh[lk4 + 1][lrow] = wv.y;
    wsh[lk4 + 2][lrow] = wv.z; wsh[lk4 + 3][lrow] = wv.w;
    __syncthreads();
#pragma unroll
    for (int k = 0; k < 16; ++k) {
      const float4 a = *(const float4*)&as[k][tr];
      const float4 b = *(const float4*)&wsh[k][tc];
      acc[0][0] += a.x * b.x; acc[0][1] += a.x * b.y; acc[0][2] += a.x * b.z; acc[0][3] += a.x * b.w;
      acc[1][0] += a.y * b.x; acc[1][1] += a.y * b.y; acc[1][2] += a.y * b.z; acc[1][3] += a.y * b.w;
      acc[2][0] += a.z * b.x; acc[2][1] += a.z * b.y; acc[2][2] += a.z * b.z; acc[2][3] += a.z * b.w;
      acc[3][0] += a.w * b.x; acc[3][1] += a.w * b.y; acc[3][2] += a.w * b.z; acc[3][3] += a.w * b.w;
    }
  }
  const float* bp0 = b0 + bn + tc;
  const float* bp1 = b1 + bn + tc;
#pragma unroll
  for (int i = 0; i < 4; ++i) {
    float* cp = C + (size_t)(bm + tr + i) * N + bn + tc;
#pragma unroll
    for (int j = 0; j < 4; ++j) cp[j] = acc[i][j] + bp0[j] + bp1[j];
  }
}

__global__ __launch_bounds__(256)
void lstm_step(const float* __restrict__ gx, long long gxstride,
               const float* __restrict__ whh,
               const float* __restrict__ hprev, long long pstride,
               float* __restrict__ hnext, long long nstride,
               float* __restrict__ cbuf) {
  __shared__ float hs[32][16];
  __shared__ float wsm[32][4][32];
  const int tid = threadIdx.x;
  const int jt = blockIdx.x << 5;
  const int bm = blockIdx.y << 4;
  const int col = tid & 31;
  const int rp = (tid >> 5) << 1;
  const int hr = tid >> 4;
  const int hk = (tid & 15) << 1;
  const int wrow = tid & 127;
  const int wg = wrow >> 5;
  const int wc = wrow & 31;
  const int wk = (tid >> 7) << 4;
  const float* wbase = whh + (size_t)(wg * HH + jt + wc) * HH + wk;
  const float* hbase = hprev + (size_t)(bm + hr) * pstride + hk;

  float acc[4][2] = {};
  for (int k0 = 0; k0 < HH; k0 += 32) {
    const float2 hv = *(const float2*)(hbase + k0);
    const float4 wv0 = *(const float4*)(wbase + k0);
    const float4 wv1 = *(const float4*)(wbase + k0 + 4);
    const float4 wv2 = *(const float4*)(wbase + k0 + 8);
    const float4 wv3 = *(const float4*)(wbase + k0 + 12);
    __syncthreads();
    hs[hk][hr] = hv.x; hs[hk + 1][hr] = hv.y;
    {
      const float wvv[16] = {wv0.x, wv0.y, wv0.z, wv0.w, wv1.x, wv1.y, wv1.z, wv1.w,
                             wv2.x, wv2.y, wv2.z, wv2.w, wv3.x, wv3.y, wv3.z, wv3.w};
#pragma unroll
      for (int i = 0; i < 16; ++i) wsm[wk + i][wg][wc] = wvv[i];
    }
    __syncthreads();
#pragma unroll
    for (int k = 0; k < 32; ++k) {
      const float2 a = *(const float2*)&hs[k][rp];
      const float wi = wsm[k][0][col];
      const float wf = wsm[k][1][col];
      const float wg_ = wsm[k][2][col];
      const float wo = wsm[k][3][col];
      acc[0][0] += a.x * wi;  acc[0][1] += a.y * wi;
      acc[1][0] += a.x * wf;  acc[1][1] += a.y * wf;
      acc[2][0] += a.x * wg_; acc[2][1] += a.y * wg_;
      acc[3][0] += a.x * wo;  acc[3][1] += a.y * wo;
    }
  }
#pragma unroll
  for (int rr = 0; rr < 2; ++rr) {
    const int b = bm + rp + rr;
    const int j = jt + col;
    const size_t gxo = (size_t)b * gxstride + j;
    const float gi = acc[0][rr] + gx[gxo];
    const float gf = acc[1][rr] + gx[gxo + HH];
    const float gg = acc[2][rr] + gx[gxo + 2 * HH];
    const float go = acc[3][rr] + gx[gxo + 3 * HH];
    const float si = 1.f / (1.f + expf(-gi));
    const float sf = 1.f / (1.f + expf(-gf));
    const float so = 1.f / (1.f + expf(-go));
    const size_t cidx = (size_t)b * HH + j;
    const float cn = sf * cbuf[cidx] + si * tanhf(gg);
    cbuf[cidx] = cn;
    hnext[(size_t)b * nstride + j] = so * tanhf(cn);
  }
}

__global__ __launch_bounds__(256)
void fc_kernel(const float* __restrict__ hlast, const float* __restrict__ fcw,
               const float* __restrict__ fcb, float* __restrict__ out) {
  const int gw = (int)((blockIdx.x * 256 + threadIdx.x) >> 6);
  const int lane = threadIdx.x & 63;
  const int b = gw / CO;
  const int n = gw - b * CO;
  const float* hp = hlast + (size_t)b * HH;
  const float* wp = fcw + (size_t)n * HH;
  float s = 0.f;
  for (int k = lane; k < HH; k += 64) s += hp[k] * wp[k];
#pragma unroll
  for (int off = 32; off; off >>= 1) s += __shfl_down(s, off);
  if (lane == 0) out[b * CO + n] = s + fcb[n];
}

// ==================================================================
extern "C" void kernel_launch(void* const* d_in, const int* in_sizes, int n_in,
                              void* d_out, int out_size, void* d_ws, size_t ws_size,
                              hipStream_t stream) {
  const float* x    = (const float*)d_in[0];
  const float* wih0 = (const float*)d_in[1];
  const float* whh0 = (const float*)d_in[2];
  const float* bih0 = (const float*)d_in[3];
  const float* bhh0 = (const float*)d_in[4];
  const float* wih1 = (const float*)d_in[5];
  const float* whh1 = (const float*)d_in[6];
  const float* bih1 = (const float*)d_in[7];
  const float* bhh1 = (const float*)d_in[8];
  const float* fcw  = (const float*)d_in[9];
  const float* fcb  = (const float*)d_in[10];
  float* out = (float*)d_out;

  // ---- MFMA-path workspace ----
  const size_t pk0B  = (size_t)256 * 48 * 512 * 2;    // 12,582,912 B (hi only)
  const size_t pk1B  = (size_t)256 * 64 * 512 * 2;    // 16,777,216 B
  const size_t ringB = (size_t)RS * SLOTE * 2;        // 8,912,896 B each
  const size_t cB    = (size_t)BB * HH * 4;           // 524,288 B
  const size_t barB  = 4096;
  const size_t needB = pk0B + pk1B + 2 * ringB + 2 * cB + barB;   // ~48.3 MB

  if (needB <= ws_size) {
    char* p = (char*)d_ws;
    unsigned short* pk0   = (unsigned short*)p; p += pk0B;
    unsigned short* pk1   = (unsigned short*)p; p += pk1B;
    unsigned short* ring0 = (unsigned short*)p; p += ringB;
    unsigned short* ring1 = (unsigned short*)p; p += ringB;
    char* zblock = p;                    // c0, c1, bar (zeroed each call)
    float* c0 = (float*)p; p += cB;
    float* c1 = (float*)p; p += cB;
    unsigned* bar = (unsigned*)p; p += barB;

    hipMemsetAsync(zblock, 0, 2 * cB + barB, stream);
    hipMemsetAsync(ring0, 0, (size_t)SLOTE * 2, stream);   // slot 0 = h0[-1] = 0
    hipMemsetAsync(ring1, 0, (size_t)SLOTE * 2, stream);   // slot 0 = h1[-1] = 0

    pack_w1<<<dim3((256 * 48 * 64) / 256), 256, 0, stream>>>(whh0, wih0, pk0, HH, DD);
    pack_w1<<<dim3((256 * 64 * 64) / 256), 256, 0, stream>>>(whh1, wih1, pk1, HH, HH);

    // cooperative chunked loop
    bool coop_ok = true;
    int barBase = 0;
    for (int t0 = 0; t0 <= TT; t0 += CHUNK) {
      int len = TT + 1 - t0; if (len > CHUNK) len = CHUNK;
      void* args[] = {(void*)&t0, (void*)&len, (void*)&barBase,
                      (void*)&x, (void*)&pk0, (void*)&pk1,
                      (void*)&ring0, (void*)&ring1,
                      (void*)&bih0, (void*)&bhh0, (void*)&bih1, (void*)&bhh1,
                      (void*)&c0, (void*)&c1, (void*)&bar};
      hipError_t ce = hipLaunchCooperativeKernel((void*)lstm_chunk,
                                                 dim3(256), dim3(512), args, 0, stream);
      if (ce != hipSuccess) { coop_ok = (t0 != 0); break; }
      barBase += len - 1;
    }
    if (!coop_ok) {
      // non-cooperative fallback: one diag-step per launch (no in-kernel barrier)
      for (int t = 0; t <= TT; ++t) {
        lstm_chunk<<<dim3(256), 512, 0, stream>>>(t, 1, 0, x, pk0, pk1, ring0, ring1,
                                                  bih0, bhh0, bih1, bhh1, c0, c1, bar);
      }
    }

    // h1[255] lives at ring1 slot (TT % RS)
    unsigned short* h1last = ring1 + (size_t)(TT % RS) * SLOTE;
    fc_hilo<<<dim3((BB * CO * 64) / 256), 256, 0, stream>>>(h1last, h1last + LOOFF,
                                                            fcw, fcb, out);
    return;
  }

  // ---------------- fallback fp32 path ----------------
  {
    int Tc2 = 64, lt2 = 6;
    while (Tc2 > 1) {
      size_t need = ((size_t)655360 * (size_t)Tc2 + 4u * 131072u + 1024u) * 4u;
      if (need <= ws_size) break;
      Tc2 >>= 1; --lt2;
    }
    float* ws  = (float*)d_ws;
    float* gxc = ws;
    float* hc  = gxc + (size_t)BB * Tc2 * G4H;
    float* c0  = hc + (size_t)BB * Tc2 * HH;
    float* c1  = c0 + (size_t)BB * HH;
    float* h2a = c1 + (size_t)BB * HH;
    float* h2b = h2a + (size_t)BB * HH;
    float* zb  = h2b + (size_t)BB * HH;

    hipMemsetAsync(zb, 0, HH * sizeof(float), stream);
    hipMemsetAsync(c0, 0, (size_t)BB * HH * sizeof(float), stream);
    hipMemsetAsync(c1, 0, (size_t)BB * HH * sizeof(float), stream);

    const dim3 gGemm(G4H / 64, (BB * Tc2) / 64);
    const dim3 gStep(HH / 32, BB / 16);
    const long long gxs = (long long)Tc2 * G4H;
    const long long hcs = (long long)Tc2 * HH;

    const int nChunks = TT / Tc2;
    for (int ci = 0; ci < nChunks; ++ci) {
      const int t0 = ci * Tc2;
      gemm_bias<<<gGemm, 256, 0, stream>>>(x + (size_t)t0 * DD, (long long)TT * DD,
                                           (long long)DD, lt2, wih0, bih0, bhh0,
                                           gxc, G4H, DD);
      for (int tl = 0; tl < Tc2; ++tl) {
        const int t = t0 + tl;
        const float* hprev;
        long long ps;
        if (t == 0) { hprev = zb; ps = 0; }
        else {
          const int ptl = (tl == 0) ? (Tc2 - 1) : (tl - 1);
          hprev = hc + (size_t)ptl * HH; ps = hcs;
        }
        lstm_step<<<gStep, 256, 0, stream>>>(gxc + (size_t)tl * G4H, gxs, whh0,
                                             hprev, ps, hc + (size_t)tl * HH, hcs, c0);
      }
      gemm_bias<<<gGemm, 256, 0, stream>>>(hc, hcs, (long long)HH, lt2,
                                           wih1, bih1, bhh1, gxc, G4H, HH);
      for (int tl = 0; tl < Tc2; ++tl) {
        const int t = t0 + tl;
        const float* hprev;
        long long ps;
        if (t == 0) { hprev = zb; ps = 0; }
        else { hprev = ((t - 1) & 1) ? h2b : h2a; ps = HH; }
        float* hnext = (t & 1) ? h2b : h2a;
        lstm_step<<<gStep, 256, 0, stream>>>(gxc + (size_t)tl * G4H, gxs, whh1,
                                             hprev, ps, hnext, HH, c1);
      }
    }
    fc_kernel<<<dim3((BB * CO * 64) / 256), 256, 0, stream>>>(h2b, fcw, fcb, out);
  }
}